// Round 10
// baseline (225.883 us; speedup 1.0000x reference)
//
#include <hip/hip_runtime.h>
#include <hip/hip_bf16.h>

// Problem constants
#define B_SZ   2
#define S_LEN  2048
#define E_DIM  1024
#define H_Q    16
#define H_KV   4
#define HD     64          // head dim
#define KV_DIM 256         // H_KV * HD
#define M_ROWS (B_SZ * S_LEN)   // 4096
#define N_QT128 (S_LEN / 128)   // 16 q-tiles (128 rows) per batch-head

typedef short bf16x4 __attribute__((ext_vector_type(4)));
typedef short bf16x8 __attribute__((ext_vector_type(8)));
typedef float f32x4  __attribute__((ext_vector_type(4)));
typedef unsigned u32x2 __attribute__((ext_vector_type(2)));

#define MFMA16x32(a, b, c) __builtin_amdgcn_mfma_f32_16x16x32_bf16(a, b, c, 0, 0, 0)

#if __has_builtin(__builtin_amdgcn_mfma_f32_16x16x16bf16_1k)
#define MFMA_PV(a, b, c) __builtin_amdgcn_mfma_f32_16x16x16bf16_1k(a, b, c, 0, 0, 0)
#elif __has_builtin(__builtin_amdgcn_mfma_f32_16x16x16_bf16)
#define MFMA_PV(a, b, c) __builtin_amdgcn_mfma_f32_16x16x16_bf16(a, b, c, 0, 0, 0)
#else
static __device__ inline f32x4 mfma_pv_asm(bf16x4 a, bf16x4 b, f32x4 c) {
    asm volatile("v_mfma_f32_16x16x16_bf16 %0, %1, %2, %0"
                 : "+v"(c) : "v"(a), "v"(b));
    return c;
}
#define MFMA_PV(a, b, c) mfma_pv_asm(a, b, c)
#endif

static __device__ __forceinline__ short f32_to_bf16(float f) {
    unsigned u = __builtin_bit_cast(unsigned, f);
    u += 0x7fffu + ((u >> 16) & 1u);      // RNE
    return (short)(u >> 16);
}

// truncating pack of two f32 -> bf16x2 (P >= 0; trunc bias tiny).
// single v_perm_b32: bytes [a2,a3,b2,b3] == (ua>>16)|(ub&0xffff0000)
static __device__ __forceinline__ unsigned pack2_trunc(float a, float b) {
    return __builtin_amdgcn_perm(__builtin_bit_cast(unsigned, b),
                                 __builtin_bit_cast(unsigned, a),
                                 0x07060302u);
}

// async global->LDS, 16B per lane. LDS dest = wave-uniform base + lane*16.
static __device__ __forceinline__ void load_lds16(const short* g, short* l) {
    __builtin_amdgcn_global_load_lds(
        (const __attribute__((address_space(1))) void*)g,
        (__attribute__((address_space(3))) void*)l, 16, 0, 0);
}

// ---------------- fused pre-pass: cast x + transpose/cast 4 weights --------
__device__ __forceinline__ void transpose_body(const float* __restrict__ W,
                                               short* __restrict__ Wt,
                                               int K, int N, int bx, int by) {
    __shared__ float t[32][33];
    const int n0 = bx * 32, k0 = by * 32;
    const int tx = threadIdx.x & 31, ty = threadIdx.x >> 5;   // 32 x 8
#pragma unroll
    for (int i = 0; i < 32; i += 8)
        t[ty + i][tx] = W[(long)(k0 + ty + i) * N + n0 + tx];
    __syncthreads();
#pragma unroll
    for (int i = 0; i < 32; i += 8)
        Wt[(long)(n0 + ty + i) * K + k0 + tx] = f32_to_bf16(t[tx][ty + i]);
}

__global__ __launch_bounds__(256)
void prep(const float* __restrict__ x,
          const float* __restrict__ Wq, const float* __restrict__ Wk,
          const float* __restrict__ Wv, const float* __restrict__ Wo,
          short* __restrict__ xbf, short* __restrict__ Wqt,
          short* __restrict__ Wkt, short* __restrict__ Wvt,
          short* __restrict__ Wot) {
    const int bid = blockIdx.x;
    if (bid < 4096) {
        const int i = bid * 256 + threadIdx.x;   // float4 index
        float4 v = ((const float4*)x)[i];
        bf16x4 o;
        o[0] = f32_to_bf16(v.x); o[1] = f32_to_bf16(v.y);
        o[2] = f32_to_bf16(v.z); o[3] = f32_to_bf16(v.w);
        ((bf16x4*)xbf)[i] = o;
    } else if (bid < 5120) {
        const int r = bid - 4096;                 // 32 x 32
        transpose_body(Wq, Wqt, E_DIM, E_DIM, r & 31, r >> 5);
    } else if (bid < 5376) {
        const int r = bid - 5120;                 // 8 x 32
        transpose_body(Wk, Wkt, E_DIM, KV_DIM, r & 7, r >> 3);
    } else if (bid < 5632) {
        const int r = bid - 5376;
        transpose_body(Wv, Wvt, E_DIM, KV_DIM, r & 7, r >> 3);
    } else {
        const int r = bid - 5632;
        transpose_body(Wo, Wot, E_DIM, E_DIM, r & 31, r >> 5);
    }
}

// ---------------- 128x64 bf16 MFMA GEMM core (BK=64, m97 staging) ----------
// C_block = A[mrow..+128][0..K) @ Bt[ncol..+64][0..K)^T
// 256 thr = 4 waves; wave w covers rows [w*32, w*32+32), all 64 cols.
// acc[i][j][r] = C[wave*32+i*16+lg*4+r][j*16+lq]
__device__ __forceinline__ void gemm128x64(const short* __restrict__ Ab,
                                           const short* __restrict__ Btb,
                                           int K, short* As, short* Bs,
                                           f32x4 acc[2][4]) {
    const int tid  = threadIdx.x;
    const int wave = tid >> 6;
    const int lane = tid & 63;
    const int lq   = lane & 15;
    const int lg   = lane >> 4;
    const int srow = lane >> 3;          // 0..7 (8 rows per wave-round)
    const int scol = (lane & 7) * 8;     // 16B chunk within 64-short row

#pragma unroll
    for (int i = 0; i < 2; ++i)
#pragma unroll
        for (int j = 0; j < 4; ++j) acc[i][j] = (f32x4){0.f, 0.f, 0.f, 0.f};

    for (int k0 = 0; k0 < K; k0 += 64) {
        __syncthreads();
#pragma unroll
        for (int it = 0; it < 4; ++it) {   // A: 128 rows, 4 rounds x 8 rows
            const int m0 = wave * 32 + it * 8;
            load_lds16(Ab + (size_t)(m0 + srow) * K + k0 + scol, As + m0 * 64);
        }
#pragma unroll
        for (int it = 0; it < 2; ++it) {   // B: 64 rows, 2 rounds x 8 rows
            const int n0 = wave * 16 + it * 8;
            load_lds16(Btb + (size_t)(n0 + srow) * K + k0 + scol, Bs + n0 * 64);
        }
        __syncthreads();
#pragma unroll
        for (int ks = 0; ks < 2; ++ks) {
            bf16x8 af[2], bfr[4];
#pragma unroll
            for (int i = 0; i < 2; ++i)
                af[i] = *(const bf16x8*)
                    &As[(wave * 32 + i * 16 + lq) * 64 + ks * 32 + lg * 8];
#pragma unroll
            for (int j = 0; j < 4; ++j)
                bfr[j] = *(const bf16x8*)
                    &Bs[(j * 16 + lq) * 64 + ks * 32 + lg * 8];
#pragma unroll
            for (int i = 0; i < 2; ++i)
#pragma unroll
                for (int j = 0; j < 4; ++j)
                    acc[i][j] = MFMA16x32(af[i], bfr[j], acc[i][j]);
        }
    }
}

// ---------------- fused QKV projection -------------------------------------
// nb 0..15: Q (scaled); nb 16..19: K; nb 20..23: V transposed to Vtg.
__global__ __launch_bounds__(256)
void qkv_gemm(const short* __restrict__ xbf,
              const short* __restrict__ Wqt, const short* __restrict__ Wkt,
              const short* __restrict__ Wvt,
              short* __restrict__ Qbf, short* __restrict__ Kbf,
              short* __restrict__ Vtg, float qscale) {
    __shared__ short As[128 * 64];
    __shared__ short Bs[64 * 64];
    const int nb = blockIdx.x;   // 0..23 (64-col block)
    const int mb = blockIdx.y;   // 0..31 (128-row block)
    const short* Bt;
    if (nb < 16)      Bt = Wqt + (size_t)nb * 64 * E_DIM;
    else if (nb < 20) Bt = Wkt + (size_t)(nb - 16) * 64 * E_DIM;
    else              Bt = Wvt + (size_t)(nb - 20) * 64 * E_DIM;

    f32x4 acc[2][4];
    gemm128x64(xbf + (size_t)mb * 128 * E_DIM, Bt, E_DIM, As, Bs, acc);

    const int lane = threadIdx.x & 63, wave = threadIdx.x >> 6;
    const int lq = lane & 15, lg = lane >> 4;

    if (nb < 20) {
        short* out; int ldc, ncol0; float alpha;
        if (nb < 16) { out = Qbf; ldc = E_DIM; ncol0 = nb * 64; alpha = qscale; }
        else { out = Kbf; ldc = KV_DIM; ncol0 = (nb - 16) * 64; alpha = 1.f; }
#pragma unroll
        for (int i = 0; i < 2; ++i)
#pragma unroll
            for (int r = 0; r < 4; ++r) {
                const size_t row =
                    (size_t)mb * 128 + wave * 32 + i * 16 + lg * 4 + r;
#pragma unroll
                for (int j = 0; j < 4; ++j)
                    out[row * ldc + ncol0 + j * 16 + lq] =
                        f32_to_bf16(acc[i][j][r] * alpha);
            }
    } else {
        const int gg = nb - 20;   // whole 64-col block is one kv head
#pragma unroll
        for (int i = 0; i < 2; ++i)
#pragma unroll
            for (int r = 0; r < 4; ++r) {
                const int row = mb * 128 + wave * 32 + i * 16 + lg * 4 + r;
                const int bb = row >> 11, s = row & 2047;
#pragma unroll
                for (int j = 0; j < 4; ++j) {
                    const int d = j * 16 + lq;
                    Vtg[((long)(gg * 2 + bb) * HD + d) * S_LEN + s] =
                        f32_to_bf16(acc[i][j][r]);
                }
            }
    }
}

// ---------------- output projection ----------------------------------------
__global__ __launch_bounds__(256)
void gemm_o(const short* __restrict__ Abf, const short* __restrict__ Wot,
            float* __restrict__ C) {
    __shared__ short As[128 * 64];
    __shared__ short Bs[64 * 64];
    const int nb = blockIdx.x;   // 0..15
    const int mb = blockIdx.y;   // 0..31
    f32x4 acc[2][4];
    gemm128x64(Abf + (size_t)mb * 128 * E_DIM,
               Wot + (size_t)nb * 64 * E_DIM, E_DIM, As, Bs, acc);

    const int lane = threadIdx.x & 63, wave = threadIdx.x >> 6;
    const int lq = lane & 15, lg = lane >> 4;
#pragma unroll
    for (int i = 0; i < 2; ++i)
#pragma unroll
        for (int r = 0; r < 4; ++r) {
            const size_t row =
                (size_t)mb * 128 + wave * 32 + i * 16 + lg * 4 + r;
#pragma unroll
            for (int j = 0; j < 4; ++j)
                C[row * E_DIM + nb * 64 + j * 16 + lq] = acc[i][j][r];
        }
}

// ---------------- MFMA flash attention (causal, GQA, split-keys) -----------
// v6: NO LDS, NO BARRIERS. One independent wave per 64-thread block owning
// 32 q-rows. K/V fragments load DIRECTLY global->registers in MFMA layout;
// K (2MB) and V (2MB) are L2-resident on every XCD, so the LDS round-trip
// (global->reg->LDS->reg + 2 barriers/tile, lockstep 4 waves) was pure
// serial latency. Waves advance independently; loads overlap compute under
// compiler waitcnt scheduling. Grid = (8 pairs, 16 h, 16 b*split*wv) =
// 2048 equal blocks (rep pairing: 17 key-tiles each, perfectly balanced).
// Unnormalized softmax (bounded scores) => split partials merge linearly.

// Process one 64-key tile against this wave's 32 q-rows, K/V from global.
// dd = (wave's min q row) - (tile's first key).
template <bool MASKED>
__device__ __forceinline__ void proc_tile(const short* __restrict__ pK,
                                          const short* __restrict__ pV,
                                          const bf16x8 (&qf)[2][2],
                                          int lq, int lg, int dd,
                                          f32x4 (&o)[2][4],
                                          f32x4 (&lsum)[2]) {
    f32x4 s[4][2];
    bool need[4][2];
#pragma unroll
    for (int c = 0; c < 4; ++c) {
        const int rel0 = c * 16 - dd;
        need[c][0] = !MASKED || (rel0 < 16);
        need[c][1] = !MASKED || (rel0 - 16 < 16);
        if (MASKED && !need[c][1]) continue;   // need0 => need1
        // K[key = c*16+lq][d = lg*8 ..] and [32 + lg*8 ..], direct global
        bf16x8 kf0 = *(const bf16x8*)(pK + (size_t)c * 16 * KV_DIM);
        bf16x8 kf1 = *(const bf16x8*)(pK + (size_t)c * 16 * KV_DIM + 32);
#pragma unroll
        for (int f = 0; f < 2; ++f) {
            if (MASKED && !need[c][f]) continue;
            f32x4 acc = (f32x4){0.f, 0.f, 0.f, 0.f};
            acc = MFMA16x32(kf0, qf[f][0], acc);
            acc = MFMA16x32(kf1, qf[f][1], acc);
            if (MASKED) {
                if (c * 16 - 16 * f - dd == 0) {   // diagonal fragment
#pragma unroll
                    for (int r = 0; r < 4; ++r)
                        if (lg * 4 + r > lq) acc[r] = -INFINITY;
                }
            }
            s[c][f] = acc;
        }
    }

    // unnormalized softmax: p = exp2(s), raw v_exp_f32
#pragma unroll
    for (int c = 0; c < 4; ++c)
#pragma unroll
        for (int f = 0; f < 2; ++f) {
            if (MASKED && !need[c][f]) continue;
#pragma unroll
            for (int r = 0; r < 4; ++r)
                s[c][f][r] = __builtin_amdgcn_exp2f(s[c][f][r]);
        }

    const bf16x4 ones4 = {(short)0x3F80, (short)0x3F80,
                          (short)0x3F80, (short)0x3F80};  // bf16 1.0
    // O += P·V ; l += P·1 (row-sum on the MFMA pipe)
#pragma unroll
    for (int c = 0; c < 4; ++c) {
        if (MASKED && !need[c][1]) continue;
        bf16x4 pa[2];
#pragma unroll
        for (int f = 0; f < 2; ++f) {
            if (MASKED && !need[c][f]) continue;
            u32x2 packed;
            packed[0] = pack2_trunc(s[c][f][0], s[c][f][1]);
            packed[1] = pack2_trunc(s[c][f][2], s[c][f][3]);
            pa[f] = __builtin_bit_cast(bf16x4, packed);
            lsum[f] = MFMA_PV(pa[f], ones4, lsum[f]);
        }
#pragma unroll
        for (int dc = 0; dc < 4; ++dc) {
            // V^T[d = dc*16+lq][key = c*16 + lg*4 ..], direct global
            bf16x4 vf = *(const bf16x4*)
                (pV + (size_t)dc * 16 * S_LEN + c * 16);
#pragma unroll
            for (int f = 0; f < 2; ++f)
                if (!MASKED || need[c][f]) o[f][dc] = MFMA_PV(pa[f], vf, o[f][dc]);
        }
    }
}

__global__ __launch_bounds__(64)
void flash_mfma(const short* __restrict__ Qb,   // (B*S, 1024) bf16, pre-scaled
                const short* __restrict__ Kb,   // (B*S, 256)  bf16
                const short* __restrict__ Vtg,  // [g*2+b][d][s] bf16
                float* __restrict__ Op,         // [split*2+b][s][1024] fp32
                float* __restrict__ Lp) {       // [split*2+b][h][s] fp32
    const int pair  = blockIdx.x;  // 0..7
    const int h     = blockIdx.y;  // 0..15
    const int zz    = blockIdx.z;  // 0..15 = wv*4 + b*2 + split
    const int wv    = zz >> 2;
    const int b     = (zz >> 1) & 1;
    const int split = zz & 1;
    const int g     = h >> 2;

    const int lane = threadIdx.x;   // 64-thread block = one wave
    const int lq   = lane & 15;     // q column in fragments
    const int lg   = lane >> 4;     // lane group 0..3

    for (int rep = 0; rep < 2; ++rep) {
        const int QT = rep ? (N_QT128 - 1 - pair) : pair;   // 0..15
        const int Q0 = QT * 128;
        // key tiles [0, 2QT+1]; split0 = [0, QT], split1 = [QT+1, 2QT+1]
        const int kt0 = split ? QT + 1 : 0;
        const int kt1 = split ? 2 * QT + 1 : QT;
        // masked tiles = last nmask of the range
        const int nmask = split ? ((QT >= 1) ? 2 : 1) : ((QT == 0) ? 1 : 0);
        const int qmin = Q0 + wv * 32;   // this wave's first q row

        const short* qrow =
            Qb + ((long)(b * S_LEN + qmin + lq)) * E_DIM + h * HD;
        bf16x8 qf[2][2];
#pragma unroll
        for (int f = 0; f < 2; ++f) {
            qf[f][0] = *(const bf16x8*)(qrow + (long)f * 16 * E_DIM + lg * 8);
            qf[f][1] = *(const bf16x8*)(qrow + (long)f * 16 * E_DIM + 32 + lg * 8);
        }

        f32x4 o[2][4];
#pragma unroll
        for (int f = 0; f < 2; ++f)
#pragma unroll
            for (int dc = 0; dc < 4; ++dc) o[f][dc] = (f32x4){0.f, 0.f, 0.f, 0.f};
        f32x4 lsum[2];
        lsum[0] = lsum[1] = (f32x4){0.f, 0.f, 0.f, 0.f};

        // per-lane fragment base pointers (advance by one tile per iter)
        const short* pK = Kb +
            ((long)b * S_LEN + (long)kt0 * 64 + lq) * KV_DIM +
            g * HD + lg * 8;
        const short* pV = Vtg +
            ((long)(g * 2 + b) * HD + lq) * S_LEN +
            (long)kt0 * 64 + lg * 4;

        for (int kt = kt0; kt <= kt1; ++kt) {
            if (kt <= kt1 - nmask) {
                proc_tile<false>(pK, pV, qf, lq, lg, 0, o, lsum);
            } else {
                const int dd = __builtin_amdgcn_readfirstlane(qmin - kt * 64);
                proc_tile<true>(pK, pV, qf, lq, lg, dd, o, lsum);
            }
            pK += (size_t)64 * KV_DIM;   // +64 keys
            pV += 64;                    // +64 s positions
        }

        // ---- epilogue: store fp32 partials (no divide)
        const long ibase = (long)(split * 2 + b) << 21;   // 2048*1024 floats
#pragma unroll
        for (int f = 0; f < 2; ++f)
#pragma unroll
            for (int r = 0; r < 4; ++r) {
                const long base = ibase +
                    ((long)(qmin + f * 16 + lg * 4 + r)) * E_DIM + h * HD + lq;
#pragma unroll
                for (int dc = 0; dc < 4; ++dc) Op[base + dc * 16] = o[f][dc][r];
            }
        // lsum[f][r] = l for q = qmin + f*16 + lg*4 + r (same across lq)
        if (lq == 0) {
#pragma unroll
            for (int f = 0; f < 2; ++f)
#pragma unroll
                for (int r = 0; r < 4; ++r)
                    Lp[((split * 2 + b) * H_Q + h) * S_LEN +
                       qmin + f * 16 + lg * 4 + r] = lsum[f][r];
        }
    }
}

// ---------------- merge split-key partials -> bf16 A -----------------------
__global__ __launch_bounds__(256)
void merge_o(const float* __restrict__ Op, const float* __restrict__ Lp,
             short* __restrict__ Abf) {
    const long idx4 = (long)blockIdx.x * 256 + threadIdx.x;  // 1M float4s
    const long e = idx4 * 4;
    const int b  = (int)(e >> 21);
    const long ei = e & ((1L << 21) - 1);
    const int s  = (int)(ei >> 10);
    const int hh = ((int)(ei & 1023)) >> 6;
    const float4 v0 = *(const float4*)(Op + ((long)(0 + b) << 21) + ei);
    const float4 v1 = *(const float4*)(Op + ((long)(2 + b) << 21) + ei);
    const float l = Lp[((0 + b) * H_Q + hh) * S_LEN + s] +
                    Lp[((2 + b) * H_Q + hh) * S_LEN + s];
    const float inv = 1.f / l;
    bf16x4 o;
    o[0] = f32_to_bf16((v0.x + v1.x) * inv);
    o[1] = f32_to_bf16((v0.y + v1.y) * inv);
    o[2] = f32_to_bf16((v0.z + v1.z) * inv);
    o[3] = f32_to_bf16((v0.w + v1.w) * inv);
    *(bf16x4*)(Abf + e) = o;
}

extern "C" void kernel_launch(void* const* d_in, const int* in_sizes, int n_in,
                              void* d_out, int out_size, void* d_ws, size_t ws_size,
                              hipStream_t stream) {
    const float* x  = (const float*)d_in[0];   // (B,S,E)
    const float* Wq = (const float*)d_in[1];   // (E,E)
    const float* Wk = (const float*)d_in[2];   // (E,256)
    const float* Wv = (const float*)d_in[3];   // (E,256)
    const float* Wo = (const float*)d_in[4];   // (E,E)
    float* out = (float*)d_out;

    short* xbf = (short*)d_ws;                          // 4096x1024
    short* Wqt = xbf + (size_t)M_ROWS * E_DIM;          // 1024x1024 [n][k]
    short* Wkt = Wqt + (size_t)E_DIM * E_DIM;           // 256x1024  [n][k]
    short* Wvt = Wkt + (size_t)KV_DIM * E_DIM;          // 256x1024
    short* Wot = Wvt + (size_t)KV_DIM * E_DIM;          // 1024x1024
    short* Qbf = Wot + (size_t)E_DIM * E_DIM;           // 4096x1024
    short* Kbf = Qbf + (size_t)M_ROWS * E_DIM;          // 4096x256
    short* Vtg = Kbf + (size_t)M_ROWS * KV_DIM;         // [8][64][2048]
    short* Abf = Vtg + (size_t)8 * HD * S_LEN;          // 4096x1024
    float* Op  = (float*)(Abf + (size_t)M_ROWS * E_DIM); // [4][2048][1024] f32
    float* Lp  = Op + (size_t)4 * S_LEN * E_DIM;         // [4][16][2048]  f32

    const float qscale = 0.125f * 1.44269504088896340736f;  // 1/sqrt(64)*log2e

    prep<<<dim3(6656), dim3(256), 0, stream>>>(
        x, Wq, Wk, Wv, Wo, xbf, Wqt, Wkt, Wvt, Wot);
    qkv_gemm<<<dim3(24, M_ROWS / 128), dim3(256), 0, stream>>>(
        xbf, Wqt, Wkt, Wvt, Qbf, Kbf, Vtg, qscale);
    flash_mfma<<<dim3(8, H_Q, 16), dim3(64), 0, stream>>>(
        Qbf, Kbf, Vtg, Op, Lp);
    merge_o<<<dim3(M_ROWS * E_DIM / 4 / 256), dim3(256), 0, stream>>>(
        Op, Lp, Abf);
    gemm_o<<<dim3(E_DIM / 64, M_ROWS / 128), dim3(256), 0, stream>>>(
        Abf, Wot, out);
}

// Round 11
// 164.440 us; speedup vs baseline: 1.3737x; 1.3737x over previous
//
#include <hip/hip_runtime.h>
#include <hip/hip_bf16.h>

// Problem constants
#define B_SZ   2
#define S_LEN  2048
#define E_DIM  1024
#define H_Q    16
#define H_KV   4
#define HD     64          // head dim
#define KV_DIM 256         // H_KV * HD
#define M_ROWS (B_SZ * S_LEN)   // 4096
#define N_QT128 (S_LEN / 128)   // 16 q-tiles (128 rows) per batch-head

typedef short bf16x4 __attribute__((ext_vector_type(4)));
typedef short bf16x8 __attribute__((ext_vector_type(8)));
typedef float f32x4  __attribute__((ext_vector_type(4)));
typedef unsigned u32x2 __attribute__((ext_vector_type(2)));

#define MFMA16x32(a, b, c) __builtin_amdgcn_mfma_f32_16x16x32_bf16(a, b, c, 0, 0, 0)

#if __has_builtin(__builtin_amdgcn_mfma_f32_16x16x16bf16_1k)
#define MFMA_PV(a, b, c) __builtin_amdgcn_mfma_f32_16x16x16bf16_1k(a, b, c, 0, 0, 0)
#elif __has_builtin(__builtin_amdgcn_mfma_f32_16x16x16_bf16)
#define MFMA_PV(a, b, c) __builtin_amdgcn_mfma_f32_16x16x16_bf16(a, b, c, 0, 0, 0)
#else
static __device__ inline f32x4 mfma_pv_asm(bf16x4 a, bf16x4 b, f32x4 c) {
    asm volatile("v_mfma_f32_16x16x16_bf16 %0, %1, %2, %0"
                 : "+v"(c) : "v"(a), "v"(b));
    return c;
}
#define MFMA_PV(a, b, c) mfma_pv_asm(a, b, c)
#endif

static __device__ __forceinline__ short f32_to_bf16(float f) {
    unsigned u = __builtin_bit_cast(unsigned, f);
    u += 0x7fffu + ((u >> 16) & 1u);      // RNE
    return (short)(u >> 16);
}

// truncating pack of two f32 -> bf16x2 (P >= 0; trunc bias tiny).
// single v_perm_b32: bytes [a2,a3,b2,b3] == (ua>>16)|(ub&0xffff0000)
static __device__ __forceinline__ unsigned pack2_trunc(float a, float b) {
    return __builtin_amdgcn_perm(__builtin_bit_cast(unsigned, b),
                                 __builtin_bit_cast(unsigned, a),
                                 0x07060302u);
}

// async global->LDS, 16B per lane. LDS dest = wave-uniform base + lane*16.
static __device__ __forceinline__ void load_lds16(const short* g, short* l) {
    __builtin_amdgcn_global_load_lds(
        (const __attribute__((address_space(1))) void*)g,
        (__attribute__((address_space(3))) void*)l, 16, 0, 0);
}

// ---------------- fused pre-pass: cast x + transpose/cast 4 weights --------
__device__ __forceinline__ void transpose_body(const float* __restrict__ W,
                                               short* __restrict__ Wt,
                                               int K, int N, int bx, int by) {
    __shared__ float t[32][33];
    const int n0 = bx * 32, k0 = by * 32;
    const int tx = threadIdx.x & 31, ty = threadIdx.x >> 5;   // 32 x 8
#pragma unroll
    for (int i = 0; i < 32; i += 8)
        t[ty + i][tx] = W[(long)(k0 + ty + i) * N + n0 + tx];
    __syncthreads();
#pragma unroll
    for (int i = 0; i < 32; i += 8)
        Wt[(long)(n0 + ty + i) * K + k0 + tx] = f32_to_bf16(t[tx][ty + i]);
}

__global__ __launch_bounds__(256)
void prep(const float* __restrict__ x,
          const float* __restrict__ Wq, const float* __restrict__ Wk,
          const float* __restrict__ Wv, const float* __restrict__ Wo,
          short* __restrict__ xbf, short* __restrict__ Wqt,
          short* __restrict__ Wkt, short* __restrict__ Wvt,
          short* __restrict__ Wot) {
    const int bid = blockIdx.x;
    if (bid < 4096) {
        const int i = bid * 256 + threadIdx.x;   // float4 index
        float4 v = ((const float4*)x)[i];
        bf16x4 o;
        o[0] = f32_to_bf16(v.x); o[1] = f32_to_bf16(v.y);
        o[2] = f32_to_bf16(v.z); o[3] = f32_to_bf16(v.w);
        ((bf16x4*)xbf)[i] = o;
    } else if (bid < 5120) {
        const int r = bid - 4096;                 // 32 x 32
        transpose_body(Wq, Wqt, E_DIM, E_DIM, r & 31, r >> 5);
    } else if (bid < 5376) {
        const int r = bid - 5120;                 // 8 x 32
        transpose_body(Wk, Wkt, E_DIM, KV_DIM, r & 7, r >> 3);
    } else if (bid < 5632) {
        const int r = bid - 5376;
        transpose_body(Wv, Wvt, E_DIM, KV_DIM, r & 7, r >> 3);
    } else {
        const int r = bid - 5632;
        transpose_body(Wo, Wot, E_DIM, E_DIM, r & 31, r >> 5);
    }
}

// ---------------- 128x64 bf16 MFMA GEMM core (BK=64, m97 staging) ----------
// C_block = A[mrow..+128][0..K) @ Bt[ncol..+64][0..K)^T
// 256 thr = 4 waves; wave w covers rows [w*32, w*32+32), all 64 cols.
// acc[i][j][r] = C[wave*32+i*16+lg*4+r][j*16+lq]
__device__ __forceinline__ void gemm128x64(const short* __restrict__ Ab,
                                           const short* __restrict__ Btb,
                                           int K, short* As, short* Bs,
                                           f32x4 acc[2][4]) {
    const int tid  = threadIdx.x;
    const int wave = tid >> 6;
    const int lane = tid & 63;
    const int lq   = lane & 15;
    const int lg   = lane >> 4;
    const int srow = lane >> 3;          // 0..7 (8 rows per wave-round)
    const int scol = (lane & 7) * 8;     // 16B chunk within 64-short row

#pragma unroll
    for (int i = 0; i < 2; ++i)
#pragma unroll
        for (int j = 0; j < 4; ++j) acc[i][j] = (f32x4){0.f, 0.f, 0.f, 0.f};

    for (int k0 = 0; k0 < K; k0 += 64) {
        __syncthreads();
#pragma unroll
        for (int it = 0; it < 4; ++it) {   // A: 128 rows, 4 rounds x 8 rows
            const int m0 = wave * 32 + it * 8;
            load_lds16(Ab + (size_t)(m0 + srow) * K + k0 + scol, As + m0 * 64);
        }
#pragma unroll
        for (int it = 0; it < 2; ++it) {   // B: 64 rows, 2 rounds x 8 rows
            const int n0 = wave * 16 + it * 8;
            load_lds16(Btb + (size_t)(n0 + srow) * K + k0 + scol, Bs + n0 * 64);
        }
        __syncthreads();
#pragma unroll
        for (int ks = 0; ks < 2; ++ks) {
            bf16x8 af[2], bfr[4];
#pragma unroll
            for (int i = 0; i < 2; ++i)
                af[i] = *(const bf16x8*)
                    &As[(wave * 32 + i * 16 + lq) * 64 + ks * 32 + lg * 8];
#pragma unroll
            for (int j = 0; j < 4; ++j)
                bfr[j] = *(const bf16x8*)
                    &Bs[(j * 16 + lq) * 64 + ks * 32 + lg * 8];
#pragma unroll
            for (int i = 0; i < 2; ++i)
#pragma unroll
                for (int j = 0; j < 4; ++j)
                    acc[i][j] = MFMA16x32(af[i], bfr[j], acc[i][j]);
        }
    }
}

// ---------------- fused QKV projection -------------------------------------
// nb 0..15: Q (scaled); nb 16..19: K; nb 20..23: V transposed to Vtg.
__global__ __launch_bounds__(256)
void qkv_gemm(const short* __restrict__ xbf,
              const short* __restrict__ Wqt, const short* __restrict__ Wkt,
              const short* __restrict__ Wvt,
              short* __restrict__ Qbf, short* __restrict__ Kbf,
              short* __restrict__ Vtg, float qscale) {
    __shared__ short As[128 * 64];
    __shared__ short Bs[64 * 64];
    const int nb = blockIdx.x;   // 0..23 (64-col block)
    const int mb = blockIdx.y;   // 0..31 (128-row block)
    const short* Bt;
    if (nb < 16)      Bt = Wqt + (size_t)nb * 64 * E_DIM;
    else if (nb < 20) Bt = Wkt + (size_t)(nb - 16) * 64 * E_DIM;
    else              Bt = Wvt + (size_t)(nb - 20) * 64 * E_DIM;

    f32x4 acc[2][4];
    gemm128x64(xbf + (size_t)mb * 128 * E_DIM, Bt, E_DIM, As, Bs, acc);

    const int lane = threadIdx.x & 63, wave = threadIdx.x >> 6;
    const int lq = lane & 15, lg = lane >> 4;

    if (nb < 20) {
        short* out; int ldc, ncol0; float alpha;
        if (nb < 16) { out = Qbf; ldc = E_DIM; ncol0 = nb * 64; alpha = qscale; }
        else { out = Kbf; ldc = KV_DIM; ncol0 = (nb - 16) * 64; alpha = 1.f; }
#pragma unroll
        for (int i = 0; i < 2; ++i)
#pragma unroll
            for (int r = 0; r < 4; ++r) {
                const size_t row =
                    (size_t)mb * 128 + wave * 32 + i * 16 + lg * 4 + r;
#pragma unroll
                for (int j = 0; j < 4; ++j)
                    out[row * ldc + ncol0 + j * 16 + lq] =
                        f32_to_bf16(acc[i][j][r] * alpha);
            }
    } else {
        const int gg = nb - 20;   // whole 64-col block is one kv head
#pragma unroll
        for (int i = 0; i < 2; ++i)
#pragma unroll
            for (int r = 0; r < 4; ++r) {
                const int row = mb * 128 + wave * 32 + i * 16 + lg * 4 + r;
                const int bb = row >> 11, s = row & 2047;
#pragma unroll
                for (int j = 0; j < 4; ++j) {
                    const int d = j * 16 + lq;
                    Vtg[((long)(gg * 2 + bb) * HD + d) * S_LEN + s] =
                        f32_to_bf16(acc[i][j][r]);
                }
            }
    }
}

// ---------------- output projection ----------------------------------------
__global__ __launch_bounds__(256)
void gemm_o(const short* __restrict__ Abf, const short* __restrict__ Wot,
            float* __restrict__ C) {
    __shared__ short As[128 * 64];
    __shared__ short Bs[64 * 64];
    const int nb = blockIdx.x;   // 0..15
    const int mb = blockIdx.y;   // 0..31
    f32x4 acc[2][4];
    gemm128x64(Abf + (size_t)mb * 128 * E_DIM,
               Wot + (size_t)nb * 64 * E_DIM, E_DIM, As, Bs, acc);

    const int lane = threadIdx.x & 63, wave = threadIdx.x >> 6;
    const int lq = lane & 15, lg = lane >> 4;
#pragma unroll
    for (int i = 0; i < 2; ++i)
#pragma unroll
        for (int r = 0; r < 4; ++r) {
            const size_t row =
                (size_t)mb * 128 + wave * 32 + i * 16 + lg * 4 + r;
#pragma unroll
            for (int j = 0; j < 4; ++j)
                C[row * E_DIM + nb * 64 + j * 16 + lq] = acc[i][j][r];
        }
}

// ---------------- MFMA flash attention (causal, GQA, split-keys) -----------
// v2 (best-known, R3/R7 = 165.5us): 128-q blocks, each wave owns 32 q-rows
// (2 fragments); K/V fragment LDS reads feed 2 MFMAs each. Paired q-tiles
// (i, 15-i); keys split in 2 across grid.z => 512 blocks, 17 key-tiles per
// block per split (balanced). Single-buffer LDS + register prefetch.
// Falsified alternatives (do not revisit): LDS dbuf (R5, +1.5us), grid-
// unrolled occupancy (R8, makespan imbalance), in-kernel fence merge
// (R7->R8, +180us), no-LDS direct-global fragments (R9->R10, +58us:
// fragment loads are inherently uncoalesced; LDS staging IS the coalescer).
// Unnormalized softmax (bounded scores) => split partials merge linearly.
struct KVregs { bf16x8 k[2], v[2]; };

__device__ __forceinline__ void stage_load(const short*& pK, const short*& pV,
                                           KVregs& kv) {
#pragma unroll
    for (int it = 0; it < 2; ++it) {
        kv.k[it] = *(const bf16x8*)(pK + (size_t)it * 32 * KV_DIM);
        kv.v[it] = *(const bf16x8*)(pV + (size_t)it * 32 * S_LEN);
    }
    pK += (size_t)64 * KV_DIM;   // +64 keys
    pV += 64;                    // +64 s positions
}

__device__ __forceinline__ void stage_write(short (*Ks)[72], short (*Vt)[72],
                                            const KVregs& kv) {
    const int tid = threadIdx.x;
#pragma unroll
    for (int it = 0; it < 2; ++it) {
        const int c   = tid + it * 256;
        const int row = c >> 3;
        const int ch  = c & 7;
        *(bf16x8*)&Ks[row][ch * 8] = kv.k[it];
        *(bf16x8*)&Vt[row][ch * 8] = kv.v[it];
    }
}

// Process one 64-key tile against this wave's 32 q-rows.
// dd = (wave's min q row) - (tile's first key). All chunk/frag offsets are
// multiples of 16, so each (c,f) is full-pass (rel<=-16), standard triangle
// (rel==0), or full-skip (rel>=16).
template <bool MASKED>
__device__ __forceinline__ void proc_tile(const short (*Ks)[72],
                                          const short (*Vt)[72],
                                          const bf16x8 (&qf)[2][2],
                                          int lq, int lg, int dd,
                                          f32x4 (&o)[2][4],
                                          f32x4 (&lsum)[2]) {
    f32x4 s[4][2];
    bool need[4][2];
#pragma unroll
    for (int c = 0; c < 4; ++c) {
        const int rel0 = c * 16 - dd;
        need[c][0] = !MASKED || (rel0 < 16);
        need[c][1] = !MASKED || (rel0 - 16 < 16);
        if (MASKED && !need[c][1]) continue;   // need0 => need1
        bf16x8 kf0 = *(const bf16x8*)&Ks[c * 16 + lq][lg * 8];
        bf16x8 kf1 = *(const bf16x8*)&Ks[c * 16 + lq][32 + lg * 8];
#pragma unroll
        for (int f = 0; f < 2; ++f) {
            if (MASKED && !need[c][f]) continue;
            f32x4 acc = (f32x4){0.f, 0.f, 0.f, 0.f};
            acc = MFMA16x32(kf0, qf[f][0], acc);
            acc = MFMA16x32(kf1, qf[f][1], acc);
            if (MASKED) {
                if (c * 16 - 16 * f - dd == 0) {   // diagonal fragment
#pragma unroll
                    for (int r = 0; r < 4; ++r)
                        if (lg * 4 + r > lq) acc[r] = -INFINITY;
                }
            }
            s[c][f] = acc;
        }
    }

    // unnormalized softmax: p = exp2(s), raw v_exp_f32
#pragma unroll
    for (int c = 0; c < 4; ++c)
#pragma unroll
        for (int f = 0; f < 2; ++f) {
            if (MASKED && !need[c][f]) continue;
#pragma unroll
            for (int r = 0; r < 4; ++r)
                s[c][f][r] = __builtin_amdgcn_exp2f(s[c][f][r]);
        }

    const bf16x4 ones4 = {(short)0x3F80, (short)0x3F80,
                          (short)0x3F80, (short)0x3F80};  // bf16 1.0
    // O += P·V ; l += P·1 (row-sum on the MFMA pipe)
#pragma unroll
    for (int c = 0; c < 4; ++c) {
        if (MASKED && !need[c][1]) continue;
        bf16x4 pa[2];
#pragma unroll
        for (int f = 0; f < 2; ++f) {
            if (MASKED && !need[c][f]) continue;
            u32x2 packed;
            packed[0] = pack2_trunc(s[c][f][0], s[c][f][1]);
            packed[1] = pack2_trunc(s[c][f][2], s[c][f][3]);
            pa[f] = __builtin_bit_cast(bf16x4, packed);
            lsum[f] = MFMA_PV(pa[f], ones4, lsum[f]);
        }
#pragma unroll
        for (int dc = 0; dc < 4; ++dc) {
            bf16x4 vf = *(const bf16x4*)&Vt[dc * 16 + lq][c * 16 + lg * 4];
#pragma unroll
            for (int f = 0; f < 2; ++f)
                if (!MASKED || need[c][f]) o[f][dc] = MFMA_PV(pa[f], vf, o[f][dc]);
        }
    }
}

__global__ __launch_bounds__(256)
void flash_mfma(const short* __restrict__ Qb,   // (B*S, 1024) bf16, pre-scaled
                const short* __restrict__ Kb,   // (B*S, 256)  bf16
                const short* __restrict__ Vtg,  // [g*2+b][d][s] bf16
                float* __restrict__ Op,         // [split*2+b][s][1024] fp32
                float* __restrict__ Lp) {       // [split*2+b][h][s] fp32
    const int pair  = blockIdx.x;  // 0..7
    const int h     = blockIdx.y;  // 0..15
    const int b     = blockIdx.z >> 1;
    const int split = blockIdx.z & 1;
    const int g     = h >> 2;

    const int tid  = threadIdx.x;
    const int wv   = tid >> 6;
    const int lane = tid & 63;
    const int lq   = lane & 15;   // q column in fragments
    const int lg   = lane >> 4;   // lane group 0..3

    __shared__ short Ks[64][72];  // [key][d]
    __shared__ short Vt[64][72];  // [d][key]

    for (int rep = 0; rep < 2; ++rep) {
        const int QT = rep ? (N_QT128 - 1 - pair) : pair;   // 0..15
        const int Q0 = QT * 128;
        // key tiles [0, 2QT+1]; split0 = [0, QT], split1 = [QT+1, 2QT+1]
        const int kt0 = split ? QT + 1 : 0;
        const int kt1 = split ? 2 * QT + 1 : QT;
        // masked tiles = last nmask of the range
        const int nmask = split ? ((QT >= 1) ? 2 : 1) : ((QT == 0) ? 1 : 0);
        const int qmin = Q0 + wv * 32;   // this wave's first q row

        const short* qrow =
            Qb + ((long)(b * S_LEN + qmin + lq)) * E_DIM + h * HD;
        bf16x8 qf[2][2];
#pragma unroll
        for (int f = 0; f < 2; ++f) {
            qf[f][0] = *(const bf16x8*)(qrow + (long)f * 16 * E_DIM + lg * 8);
            qf[f][1] = *(const bf16x8*)(qrow + (long)f * 16 * E_DIM + 32 + lg * 8);
        }

        f32x4 o[2][4];
#pragma unroll
        for (int f = 0; f < 2; ++f)
#pragma unroll
            for (int dc = 0; dc < 4; ++dc) o[f][dc] = (f32x4){0.f, 0.f, 0.f, 0.f};
        f32x4 lsum[2];
        lsum[0] = lsum[1] = (f32x4){0.f, 0.f, 0.f, 0.f};

        // per-lane staging pointers (advance by a constant per tile)
        const short* pK = Kb +
            ((long)b * S_LEN + (long)kt0 * 64 + (tid >> 3)) * KV_DIM +
            g * HD + (tid & 7) * 8;
        const short* pV = Vtg +
            ((long)(g * 2 + b) * HD + (tid >> 3)) * S_LEN +
            (long)kt0 * 64 + (tid & 7) * 8;

        KVregs kv;
        if (kt0 <= kt1) stage_load(pK, pV, kv);

        for (int kt = kt0; kt <= kt1; ++kt) {
            __syncthreads();              // previous tile's LDS reads done
            stage_write(Ks, Vt, kv);
            __syncthreads();
            if (kt < kt1)                 // issue next global loads early
                stage_load(pK, pV, kv);

            if (kt <= kt1 - nmask) {
                proc_tile<false>(Ks, Vt, qf, lq, lg, 0, o, lsum);
            } else {
                const int dd = __builtin_amdgcn_readfirstlane(qmin - kt * 64);
                proc_tile<true>(Ks, Vt, qf, lq, lg, dd, o, lsum);
            }
        }

        // ---- epilogue: store fp32 partials (no divide)
        const long ibase = (long)(split * 2 + b) << 21;   // 2048*1024 floats
#pragma unroll
        for (int f = 0; f < 2; ++f)
#pragma unroll
            for (int r = 0; r < 4; ++r) {
                const long base = ibase +
                    ((long)(qmin + f * 16 + lg * 4 + r)) * E_DIM + h * HD + lq;
#pragma unroll
                for (int dc = 0; dc < 4; ++dc) Op[base + dc * 16] = o[f][dc][r];
            }
        // lsum[f][r] = l for q = qmin + f*16 + lg*4 + r (same across lq)
        if (lq == 0) {
#pragma unroll
            for (int f = 0; f < 2; ++f)
#pragma unroll
                for (int r = 0; r < 4; ++r)
                    Lp[((split * 2 + b) * H_Q + h) * S_LEN +
                       qmin + f * 16 + lg * 4 + r] = lsum[f][r];
        }
    }
}

// ---------------- merge split-key partials -> bf16 A -----------------------
__global__ __launch_bounds__(256)
void merge_o(const float* __restrict__ Op, const float* __restrict__ Lp,
             short* __restrict__ Abf) {
    const long idx4 = (long)blockIdx.x * 256 + threadIdx.x;  // 1M float4s
    const long e = idx4 * 4;
    const int b  = (int)(e >> 21);
    const long ei = e & ((1L << 21) - 1);
    const int s  = (int)(ei >> 10);
    const int hh = ((int)(ei & 1023)) >> 6;
    const float4 v0 = *(const float4*)(Op + ((long)(0 + b) << 21) + ei);
    const float4 v1 = *(const float4*)(Op + ((long)(2 + b) << 21) + ei);
    const float l = Lp[((0 + b) * H_Q + hh) * S_LEN + s] +
                    Lp[((2 + b) * H_Q + hh) * S_LEN + s];
    const float inv = 1.f / l;
    bf16x4 o;
    o[0] = f32_to_bf16((v0.x + v1.x) * inv);
    o[1] = f32_to_bf16((v0.y + v1.y) * inv);
    o[2] = f32_to_bf16((v0.z + v1.z) * inv);
    o[3] = f32_to_bf16((v0.w + v1.w) * inv);
    *(bf16x4*)(Abf + e) = o;
}

extern "C" void kernel_launch(void* const* d_in, const int* in_sizes, int n_in,
                              void* d_out, int out_size, void* d_ws, size_t ws_size,
                              hipStream_t stream) {
    const float* x  = (const float*)d_in[0];   // (B,S,E)
    const float* Wq = (const float*)d_in[1];   // (E,E)
    const float* Wk = (const float*)d_in[2];   // (E,256)
    const float* Wv = (const float*)d_in[3];   // (E,256)
    const float* Wo = (const float*)d_in[4];   // (E,E)
    float* out = (float*)d_out;

    short* xbf = (short*)d_ws;                          // 4096x1024
    short* Wqt = xbf + (size_t)M_ROWS * E_DIM;          // 1024x1024 [n][k]
    short* Wkt = Wqt + (size_t)E_DIM * E_DIM;           // 256x1024  [n][k]
    short* Wvt = Wkt + (size_t)KV_DIM * E_DIM;          // 256x1024
    short* Wot = Wvt + (size_t)KV_DIM * E_DIM;          // 1024x1024
    short* Qbf = Wot + (size_t)E_DIM * E_DIM;           // 4096x1024
    short* Kbf = Qbf + (size_t)M_ROWS * E_DIM;          // 4096x256
    short* Vtg = Kbf + (size_t)M_ROWS * KV_DIM;         // [8][64][2048]
    short* Abf = Vtg + (size_t)8 * HD * S_LEN;          // 4096x1024
    float* Op  = (float*)(Abf + (size_t)M_ROWS * E_DIM); // [4][2048][1024] f32
    float* Lp  = Op + (size_t)4 * S_LEN * E_DIM;         // [4][16][2048]  f32

    const float qscale = 0.125f * 1.44269504088896340736f;  // 1/sqrt(64)*log2e

    prep<<<dim3(6656), dim3(256), 0, stream>>>(
        x, Wq, Wk, Wv, Wo, xbf, Wqt, Wkt, Wvt, Wot);
    qkv_gemm<<<dim3(24, M_ROWS / 128), dim3(256), 0, stream>>>(
        xbf, Wqt, Wkt, Wvt, Qbf, Kbf, Vtg, qscale);
    flash_mfma<<<dim3(8, H_Q, 4), dim3(256), 0, stream>>>(
        Qbf, Kbf, Vtg, Op, Lp);
    merge_o<<<dim3(M_ROWS * E_DIM / 4 / 256), dim3(256), 0, stream>>>(
        Op, Lp, Abf);
    gemm_o<<<dim3(E_DIM / 64, M_ROWS / 128), dim3(256), 0, stream>>>(
        Abf, Wot, out);
}